// Round 6
// baseline (153.532 us; speedup 1.0000x reference)
//
#include <hip/hip_runtime.h>
#include <math.h>

// Problem constants (fixed by reference): B=32, T=2048, D=128
constexpr int B   = 32;
constexpr int T   = 2048;
constexpr int D   = 128;
constexpr int TB  = 32;          // output rows per block
constexpr int W   = 8;           // halo rows each side
constexpr int RT  = TB + 2 * W;  // 48 rows staged per block
constexpr int RG  = 8;           // row-groups
constexpr int RPT = RT / RG;     // 6 rows per thread
constexpr int NT  = T / TB;      // 64 tiles per sequence
constexpr int CHUNKS = RT * D * 4 / 1024;  // 24 x 1KiB DMA chunks per array
constexpr int CPW    = CHUNKS / 4;         // 6 chunks per wave per array

// R5: HBM->LDS DMA staging via global_load_lds (width 16). Register-landing
// loads cap per-CU outstanding bytes (allocator recycles dest VGPRs with
// waitcnt) -> ~2 TB/s in R1-R4. DMA staging has zero VGPR landing cost: each
// wave issues 12 independent 1KiB chunks (v+mask region, 48 rows x 512B),
// 96KB outstanding/CU at 2 blocks/CU. times rows ride in registers and drain
// at the same barrier. Scan structure = R4 (absmax 0.0 verified).
#define GL2LDS(g, l) __builtin_amdgcn_global_load_lds(                      \
    (const __attribute__((address_space(1))) void*)(g),                     \
    (__attribute__((address_space(3))) void*)(l), 16, 0, 0)

__global__ __launch_bounds__(256)
void linterp_kernel(const float* __restrict__ values,
                    const float* __restrict__ times,
                    const int*   __restrict__ mask,
                    float*       __restrict__ out)
{
    __shared__ float sV[RT * D];              // 24 KB staged values
    __shared__ int   sM[RT * D];              // 24 KB staged mask
    __shared__ float sFX[RG][D];              // summaries: 16 KB total
    __shared__ float sFT[RG][D];
    __shared__ float sBX[RG][D];
    __shared__ float sBT[RG][D];

    const int tid  = threadIdx.x;
    const int dg   = tid & 31;
    const int rg   = tid >> 5;
    const int tile = blockIdx.x & (NT - 1);
    const int b    = blockIdx.x >> 6;
    const int d    = dg * 4;
    const int seqb = b * T * D;
    const int base = seqb + d;
    const int tlo  = tile * TB;
    const int row0 = tlo - W + rg * RPT;

    // ---- DMA staging: v + m regions -> LDS (all independent, no VGPR cost) ----
    {
        const int lane     = tid & 63;
        const int wv       = tid >> 6;
        const int lrow_off = lane >> 5;        // 0/1: which row of the chunk
        const int lcol     = (lane & 31) * 4;  // float index within row
#pragma unroll
        for (int k = 0; k < CPW; ++k) {
            const int c = wv * CPW + k;        // chunk id: wave-uniform
            int r = tlo - W + 2 * c + lrow_off;
            r = min(max(r, 0), T - 1);         // clamp halo OOB (ignored at use)
            const int go = seqb + r * D + lcol;
            GL2LDS(values + go, &sV[c * 256]);
            GL2LDS(mask   + go, &sM[c * 256]);
        }
    }

    // ---- own t rows -> registers (independent; drained by same barrier) ----
    float4 tv[RPT];
#pragma unroll
    for (int i = 0; i < RPT; ++i) {
        int r = row0 + i;
        r = min(max(r, 0), T - 1);
        tv[i] = *(const float4*)(times + base + r * D);
    }

    __syncthreads();   // drains vmcnt(0) incl. DMA, then barrier

    // ---- phase A: read own rows from LDS, build fwd/bwd summaries ----
    float4 vv[RPT];
    unsigned int mb[4] = {0u, 0u, 0u, 0u};
    {
        float fX[4], fT[4], bX[4], bT[4];
#pragma unroll
        for (int j = 0; j < 4; ++j) { fX[j] = 0.f; fT[j] = -1.f; bX[j] = 0.f; bT[j] = -1.f; }
#pragma unroll
        for (int i = 0; i < RPT; ++i) {
            const int lr = rg * RPT + i;
            vv[i] = *(const float4*)&sV[lr * D + d];
            const int4 m = *(const int4*)&sM[lr * D + d];
            const int r = row0 + i;
            const bool rv = (r >= 0) && (r < T);
            mb[0] |= ((m.x != 0) && rv ? 1u : 0u) << i;
            mb[1] |= ((m.y != 0) && rv ? 1u : 0u) << i;
            mb[2] |= ((m.z != 0) && rv ? 1u : 0u) << i;
            mb[3] |= ((m.w != 0) && rv ? 1u : 0u) << i;
            const float* xp = (const float*)&vv[i];
            const float* tp = (const float*)&tv[i];
#pragma unroll
            for (int j = 0; j < 4; ++j) {
                if ((mb[j] >> i) & 1u) {
                    fX[j] = xp[j]; fT[j] = tp[j];
                    if (bT[j] < 0.f) { bX[j] = xp[j]; bT[j] = tp[j]; }
                }
            }
        }
        *(float4*)&sFX[rg][d] = make_float4(fX[0], fX[1], fX[2], fX[3]);
        *(float4*)&sFT[rg][d] = make_float4(fT[0], fT[1], fT[2], fT[3]);
        *(float4*)&sBX[rg][d] = make_float4(bX[0], bX[1], bX[2], bX[3]);
        *(float4*)&sBT[rg][d] = make_float4(bT[0], bT[1], bT[2], bT[3]);
    }
    __syncthreads();

    if (rg >= 1 && rg <= 6) {   // rg0 / rg7 are pure halo
        // ---- phase B: combine prefix / suffix summaries -> carries ----
        float cfX[4], cfT[4], cbX[4], cbT[4];
#pragma unroll
        for (int j = 0; j < 4; ++j) { cfX[j] = 0.f; cfT[j] = -1.f; cbX[j] = 0.f; cbT[j] = -1.f; }
        for (int r2 = 0; r2 < rg; ++r2) {        // last valid wins (nearest)
            const float4 px = *(const float4*)&sFX[r2][d];
            const float4 pt = *(const float4*)&sFT[r2][d];
            const float* pxp = (const float*)&px;
            const float* ptp = (const float*)&pt;
#pragma unroll
            for (int j = 0; j < 4; ++j)
                if (ptp[j] >= 0.f) { cfX[j] = pxp[j]; cfT[j] = ptp[j]; }
        }
        for (int r2 = RG - 1; r2 > rg; --r2) {   // nearest later group wins
            const float4 nx = *(const float4*)&sBX[r2][d];
            const float4 nt = *(const float4*)&sBT[r2][d];
            const float* nxp = (const float*)&nx;
            const float* ntp = (const float*)&nt;
#pragma unroll
            for (int j = 0; j < 4; ++j)
                if (ntp[j] >= 0.f) { cbX[j] = nxp[j]; cbT[j] = ntp[j]; }
        }

        // ---- rare fallback: whole prefix/suffix window unobserved ----
#pragma unroll
        for (int j = 0; j < 4; ++j) {
            if (cfT[j] < 0.f) {
                for (int r = tlo - W - 1; r >= 0; --r) {           // serial, rare
                    const int off = base + r * D + j;
                    if (mask[off] != 0) { cfX[j] = values[off]; cfT[j] = times[off]; break; }
                }
                if (cfT[j] < 0.f) { cfX[j] = 0.f; cfT[j] = times[base + j]; }
            }
            if (cbT[j] < 0.f) {
                for (int r = tlo + TB + W; r < T; ++r) {           // serial, rare
                    const int off = base + r * D + j;
                    if (mask[off] != 0) { cbX[j] = values[off]; cbT[j] = times[off]; break; }
                }
                if (cbT[j] < 0.f) { cbX[j] = 0.f; cbT[j] = times[base + (T - 1) * D + j]; }
            }
        }

        // ---- fwd fill own rows (x_last overwrites vv; equal when observed) ----
        float4 tl[RPT];
#pragma unroll
        for (int i = 0; i < RPT; ++i) {
            float* xp = (float*)&vv[i];
            const float* tp = (const float*)&tv[i];
            float* lp = (float*)&tl[i];
#pragma unroll
            for (int j = 0; j < 4; ++j) {
                if ((mb[j] >> i) & 1u) { cfX[j] = xp[j]; cfT[j] = tp[j]; }
                xp[j] = cfX[j];
                lp[j] = cfT[j];
            }
        }

        // ---- reverse: bwd fill + interpolate + store output rows ----
#pragma unroll
        for (int i = RPT - 1; i >= 0; --i) {
            const int r = row0 + i;
            const float* xp = (const float*)&vv[i];  // x_last (== v when obs)
            const float* tp = (const float*)&tv[i];
            const float* lp = (const float*)&tl[i];
            float4 o;
            float* op = (float*)&o;
#pragma unroll
            for (int j = 0; j < 4; ++j) {
                const bool obs = (mb[j] >> i) & 1u;
                if (obs) { cbX[j] = xp[j]; cbT[j] = tp[j]; }
                const float denom = cbT[j] - lp[j];
                const float num   = xp[j] * (cbT[j] - tp[j]) + cbX[j] * (tp[j] - lp[j]);
                const bool  safe  = (denom != 0.f);
                float xi = num / (safe ? denom : 1.f);
                xi = (safe && isfinite(xi)) ? xi : 0.f;
                op[j] = obs ? xp[j] : xi;
            }
            if (r >= tlo && r < tlo + TB)
                *(float4*)(out + base + r * D) = o;
        }
    }
}

extern "C" void kernel_launch(void* const* d_in, const int* in_sizes, int n_in,
                              void* d_out, int out_size, void* d_ws, size_t ws_size,
                              hipStream_t stream)
{
    const float* values = (const float*)d_in[0];
    const float* times  = (const float*)d_in[1];
    const int*   mask   = (const int*)d_in[2];
    float*       out    = (float*)d_out;

    linterp_kernel<<<B * NT, 256, 0, stream>>>(values, times, mask, out);  // 2048 blocks
}

// Round 7
// 137.138 us; speedup vs baseline: 1.1195x; 1.1195x over previous
//
#include <hip/hip_runtime.h>
#include <math.h>

// Problem constants (fixed by reference): B=32, T=2048, D=128
constexpr int B  = 32;
constexpr int T  = 2048;
constexpr int D  = 128;
constexpr int C  = 8;           // timesteps per thread (chunk)  [R6: 16 -> 8]
constexpr int NC = T / C;       // 256 chunks per sequence

// R6: exact R1 structure (best measured: 42 us) with ONE variable changed:
// C=16 -> C=8, doubling blocks 2048 -> 4096. Empirical law from R1-R5:
// throughput ~ waves-resident / burst-size-per-waitcnt. Smaller per-wave
// load bursts + 2 block generations per CU (backfill) should raise achieved
// BW. Probe-mask loads are issued FIRST: vmcnt is an in-order FIFO, so the
// longest dep chain (mask -> clz -> carry fetch) starts before the primary
// burst's tail drains.
__global__ __launch_bounds__(256)
void linterp_kernel(const float* __restrict__ values,
                    const float* __restrict__ times,
                    const int*   __restrict__ mask,
                    float*       __restrict__ out)
{
    const int gid   = blockIdx.x * 256 + threadIdx.x;
    const int d     = gid & (D - 1);
    const int chunk = (gid >> 7) & (NC - 1);   // D = 2^7
    const int b     = gid >> 15;               // D*NC = 2^15

    const int seq_base = b * T * D + d;        // element offset of (b, t=0, d)
    const int t0i      = chunk * C;

    // ---- probe-mask loads FIRST (feed the longest dependency chain) ----
    unsigned int pb = 0, nb = 0;
    if (chunk > 0) {
#pragma unroll
        for (int i = 0; i < C; ++i) {
            const int off = seq_base + (t0i - C + i) * D;
            pb |= (mask[off] != 0 ? 1u : 0u) << i;
        }
    }
    if (chunk < NC - 1) {
#pragma unroll
        for (int i = 0; i < C; ++i) {
            const int off = seq_base + (t0i + C + i) * D;
            nb |= (mask[off] != 0 ? 1u : 0u) << i;
        }
    }

    // ---- primary chunk loads (independent, coalesced) ----
    float v[C], tm[C];
    unsigned int mbits = 0;
#pragma unroll
    for (int i = 0; i < C; ++i) {
        const int off = seq_base + (t0i + i) * D;
        v[i]  = values[off];
        tm[i] = times[off];
        mbits |= (mask[off] != 0 ? 1u : 0u) << i;
    }

    // defaults for "no observation" match reference init values exactly:
    //   forward : x=0, t=times[b,0,d]      backward: x=0, t=times[b,T-1,d]
    const float t_first = times[seq_base];
    const float t_lastT = times[seq_base + (T - 1) * D];

    // ---- forward carry: last observed element strictly before this chunk ----
    float fx = 0.f, ft = t_first;
    if (chunk > 0) {
        if (pb != 0u) {
            const int idx = 31 - __builtin_clz(pb);          // latest observed
            const int off = seq_base + (t0i - C + idx) * D;
            fx = values[off]; ft = times[off];
        } else {
            // rare fallback (P = 2^-8): scan further back, E[2] rows
            for (int j = t0i - C - 1; j >= 0; --j) {
                const int off = seq_base + j * D;
                if (mask[off] != 0) { fx = values[off]; ft = times[off]; break; }
            }
        }
    }

    // ---- backward carry: first observed element strictly after this chunk ----
    float bx = 0.f, bt = t_lastT;
    if (chunk < NC - 1) {
        if (nb != 0u) {
            const int idx = __builtin_ctz(nb);               // earliest observed
            const int off = seq_base + (t0i + C + idx) * D;
            bx = values[off]; bt = times[off];
        } else {
            // rare fallback (P = 2^-8): scan further forward, E[2] rows
            for (int j = t0i + 2 * C; j < T; ++j) {
                const int off = seq_base + j * D;
                if (mask[off] != 0) { bx = values[off]; bt = times[off]; break; }
            }
        }
    }

    // ---- forward pass: x_last / t_last per element (cummax incl. current) ----
    float xl[C], tl[C];
#pragma unroll
    for (int i = 0; i < C; ++i) {
        if ((mbits >> i) & 1u) { fx = v[i]; ft = tm[i]; }
        xl[i] = fx;
        tl[i] = ft;
    }

    // ---- reverse pass: x_next / t_next on the fly, combine, store ----
#pragma unroll
    for (int i = C - 1; i >= 0; --i) {
        const bool obs = (mbits >> i) & 1u;
        if (obs) { bx = v[i]; bt = tm[i]; }
        const float denom = bt - tl[i];
        const float num   = xl[i] * (bt - tm[i]) + bx * (tm[i] - tl[i]);
        const bool  safe  = (denom != 0.f);
        float xi = num / (safe ? denom : 1.f);
        xi = (safe && isfinite(xi)) ? xi : 0.f;
        out[seq_base + (t0i + i) * D] = obs ? v[i] : xi;
    }
}

extern "C" void kernel_launch(void* const* d_in, const int* in_sizes, int n_in,
                              void* d_out, int out_size, void* d_ws, size_t ws_size,
                              hipStream_t stream)
{
    const float* values = (const float*)d_in[0];
    const float* times  = (const float*)d_in[1];
    const int*   mask   = (const int*)d_in[2];
    float*       out    = (float*)d_out;

    const int total_threads = B * NC * D;   // 1048576 -> 4096 blocks
    linterp_kernel<<<total_threads / 256, 256, 0, stream>>>(values, times, mask, out);
}